// Round 2
// baseline (524.677 us; speedup 1.0000x reference)
//
#include <hip/hip_runtime.h>
#include <float.h>
#include <math.h>

#define K_CODES 1024
#define ED 64
#define NTOK 131072

// ---------------------------------------------------------------------------
// numpy pairwise_sum (n=64 case): 8 accumulators strided 8, plain adds of the
// rounded products, combine ((r0+r1)+(r2+r3))+((r4+r5)+(r6+r7)).
// Must NOT be contracted into fma -> pragma contract(off) in callers.
// ---------------------------------------------------------------------------

// init: e_sq[k] = pairwise sum cb[k][d]^2 ; zero counts + sse (ws poisoned)
__global__ __launch_bounds__(1024) void vq_init(const float* __restrict__ cb,
                                                float* __restrict__ e_sq,
                                                unsigned int* __restrict__ counts,
                                                float* __restrict__ sse)
{
#pragma clang fp contract(off)
    const int k = threadIdx.x;             // single block of 1024
    const float* e = cb + k * ED;
    float r[8];
#pragma unroll
    for (int j = 0; j < 8; ++j) r[j] = e[j] * e[j];
#pragma unroll
    for (int i = 8; i < ED; i += 8)
#pragma unroll
        for (int j = 0; j < 8; ++j) r[j] = r[j] + e[i + j] * e[i + j];
    e_sq[k] = ((r[0] + r[1]) + (r[2] + r[3])) + ((r[4] + r[5]) + (r[6] + r[7]));
    counts[k] = 0u;
    if (k == 0) *sse = 0.f;
}

// ---------------------------------------------------------------------------
// main: per-token argmin over 1024 codes + fused epilogue
// ---------------------------------------------------------------------------
__global__ __launch_bounds__(256) void vq_main(const float* __restrict__ z_e,
                                               const float* __restrict__ cb,
                                               const float* __restrict__ e_sq,
                                               float* __restrict__ out_zq,
                                               float* __restrict__ out_idx,
                                               unsigned int* __restrict__ counts,
                                               float* __restrict__ sse)
{
#pragma clang fp contract(off)
    __shared__ unsigned int hist[K_CODES];
    __shared__ float wsum[4];
    for (int i = threadIdx.x; i < K_CODES; i += 256) hist[i] = 0u;
    __syncthreads();

    const int t = blockIdx.x * 256 + threadIdx.x;   // token id

    // z into registers (64 VGPRs)
    const float4* zp = (const float4*)(z_e + (size_t)t * ED);
    float zr[ED];
#pragma unroll
    for (int i = 0; i < 16; ++i) {
        float4 v = zp[i];
        zr[4 * i + 0] = v.x; zr[4 * i + 1] = v.y;
        zr[4 * i + 2] = v.z; zr[4 * i + 3] = v.w;
    }

    // |z|^2 : numpy pairwise order, plain mul + add (no fma)
    float r[8];
#pragma unroll
    for (int j = 0; j < 8; ++j) r[j] = zr[j] * zr[j];
#pragma unroll
    for (int i = 8; i < ED; i += 8)
#pragma unroll
        for (int j = 0; j < 8; ++j) r[j] = r[j] + zr[i + j] * zr[i + j];
    const float zsq =
        ((r[0] + r[1]) + (r[2] + r[3])) + ((r[4] + r[5]) + (r[6] + r[7]));

    // argmin over codes. dot = single sequential FMA chain over d (BLAS sgemm
    // micro-kernel order: one accumulator per C element, K-loop innermost).
    // ILP comes from 4 independent k-chains.
    float best = FLT_MAX;
    int bi = 0;
    for (int k = 0; k < K_CODES; k += 4) {
        const float* __restrict__ e = cb + (size_t)k * ED;   // wave-uniform
        float a0 = 0.f, a1 = 0.f, a2 = 0.f, a3 = 0.f;
#pragma unroll
        for (int d = 0; d < ED; ++d) {
            a0 = fmaf(zr[d], e[d], a0);
            a1 = fmaf(zr[d], e[d + ED], a1);
            a2 = fmaf(zr[d], e[d + 2 * ED], a2);
            a3 = fmaf(zr[d], e[d + 3 * ED], a3);
        }
        // d2 = fl(fl(zsq - 2*dot) + e_sq): fmaf(-2,dot,zsq) == fl(zsq-fl(2dot))
        float d2;
        d2 = fmaf(-2.f, a0, zsq) + e_sq[k + 0];
        if (d2 < best) { best = d2; bi = k + 0; }
        d2 = fmaf(-2.f, a1, zsq) + e_sq[k + 1];
        if (d2 < best) { best = d2; bi = k + 1; }
        d2 = fmaf(-2.f, a2, zsq) + e_sq[k + 2];
        if (d2 < best) { best = d2; bi = k + 2; }
        d2 = fmaf(-2.f, a3, zsq) + e_sq[k + 3];
        if (d2 < best) { best = d2; bi = k + 3; }
    }

    atomicAdd(&hist[bi], 1u);
    out_idx[t] = (float)bi;

    // gather selected code, write z_q, accumulate SSE
    const float4* eq = (const float4*)(cb + (size_t)bi * ED);
    float4* oz = (float4*)(out_zq + (size_t)t * ED);
    float lsse = 0.f;
#pragma unroll
    for (int i = 0; i < 16; ++i) {
        float4 q = eq[i];
        oz[i] = q;
        float dx = q.x - zr[4 * i + 0]; lsse = fmaf(dx, dx, lsse);
        float dy = q.y - zr[4 * i + 1]; lsse = fmaf(dy, dy, lsse);
        float dz = q.z - zr[4 * i + 2]; lsse = fmaf(dz, dz, lsse);
        float dw = q.w - zr[4 * i + 3]; lsse = fmaf(dw, dw, lsse);
    }

    // wave64 reduce, then 4 waves -> block, one atomic per block
#pragma unroll
    for (int off = 32; off > 0; off >>= 1)
        lsse += __shfl_down(lsse, off, 64);
    const int lane = threadIdx.x & 63;
    const int wid  = threadIdx.x >> 6;
    if (lane == 0) wsum[wid] = lsse;
    __syncthreads();
    if (threadIdx.x == 0)
        atomicAdd(sse, (wsum[0] + wsum[1]) + (wsum[2] + wsum[3]));

    // flush histogram (device-scope atomics are cross-XCD safe)
    for (int i = threadIdx.x; i < K_CODES; i += 256) {
        const unsigned int c = hist[i];
        if (c) atomicAdd(&counts[i], c);
    }
}

// ---------------------------------------------------------------------------
// final: entropy / losses scalars
// ---------------------------------------------------------------------------
__global__ __launch_bounds__(1024) void vq_final(const unsigned int* __restrict__ counts,
                                                 const float* __restrict__ sse,
                                                 float* __restrict__ out_sc)
{
    __shared__ float red[1024];
    const int i = threadIdx.x;
    const float c = (float)counts[i];
    const float p = c / (float)NTOK + 1e-10f;
    red[i] = p * logf(p);
    __syncthreads();
    for (int s = 512; s > 0; s >>= 1) {
        if (i < s) red[i] += red[i + s];
        __syncthreads();
    }
    if (i == 0) {
        const float entropy = -red[0];
        const float cbl = (*sse) / ((float)NTOK * (float)ED);
        out_sc[0] = cbl;                                   // codebook_loss
        out_sc[1] = 0.25f * cbl;                           // commitment_loss
        out_sc[2] = -0.1f * (entropy / 6.93147180559945f); // entropy_loss
        out_sc[3] = expf(entropy);                         // perplexity
    }
}

// ---------------------------------------------------------------------------
extern "C" void kernel_launch(void* const* d_in, const int* in_sizes, int n_in,
                              void* d_out, int out_size, void* d_ws, size_t ws_size,
                              hipStream_t stream)
{
    const float* z_e = (const float*)d_in[0];
    const float* cb  = (const float*)d_in[1];

    float* out   = (float*)d_out;
    float* o_zq  = out;                              // [131072,64]
    float* o_idx = out + (size_t)NTOK * ED;          // [131072] (as float)
    float* o_sc  = o_idx + NTOK;                     // 4 scalars

    float*        e_sq   = (float*)d_ws;                          // 4 KB
    unsigned int* counts = (unsigned int*)((char*)d_ws + 4096);   // 4 KB
    float*        sse    = (float*)((char*)d_ws + 8192);          // 4 B

    vq_init <<<1, 1024, 0, stream>>>(cb, e_sq, counts, sse);
    vq_main <<<NTOK / 256, 256, 0, stream>>>(z_e, cb, e_sq, o_zq, o_idx, counts, sse);
    vq_final<<<1, 1024, 0, stream>>>(counts, sse, o_sc);
}